// Round 16
// baseline (120.859 us; speedup 1.0000x reference)
//
#include <hip/hip_runtime.h>
#include <hip/hip_bf16.h>

typedef __attribute__((ext_vector_type(8))) short bf16x8;
typedef __attribute__((ext_vector_type(4))) float f32x4;

#define NCOLP 384                 // padded columns (352 real + 32 zero)
#define STEP_SHORTS (NCOLP * 32)  // 12288 shorts = 24576 B per 32-k step
#define STEP_BYTES 24576
#define SEG_BYTES 6144            // Wpack per-ablk segment: 384 cols * 8k * 2B
#define NSTEP 32
#define HSTEP 16
#define BROWS 65536

static __device__ __forceinline__ unsigned int bf16rne(float f) {
  unsigned int u = __float_as_uint(f);
  return (u + 0x7FFFu + ((u >> 16) & 1u)) >> 16;
}
static __device__ __forceinline__ unsigned int pack2(float a, float b) {
  return bf16rne(a) | (bf16rne(b) << 16);
}

// Wpack layout: [step][ablk(4)][col(384)][k%8] (bf16), 24576 B/step.
// Column map: [0,100) task0 (e*10+h), [100,200) task1, [200,300) shared,
// [300,340) gates (t*20+g), [340,384) zero pad.
__global__ void ple_prep(const float* __restrict__ Ws, const float* __restrict__ bs,
                         const float* __restrict__ Wt, const float* __restrict__ bt,
                         const float* __restrict__ Wg, const float* __restrict__ bg,
                         unsigned short* __restrict__ Wpack, float* __restrict__ bias) {
  const int n = blockIdx.x;  // 0..383
  const int tid = threadIdx.x;
  const float* src = nullptr;
  int stride = 0;
  float bval = 0.f;
  if (n < 200) {
    int t = n / 100, m = n % 100, e = m / 10, h = m % 10;
    src = Wt + (size_t)(t * 10 + e) * 10240 + h;
    stride = 10;
    bval = bt[(t * 10 + e) * 10 + h];
  } else if (n < 300) {
    int m = n - 200, e = m / 10, h = m % 10;
    src = Ws + (size_t)e * 10240 + h;
    stride = 10;
    bval = bs[e * 10 + h];
  } else if (n < 340) {
    int m = n - 300, t = m / 20, g = m % 20;
    src = Wg + (size_t)t * 20480 + g;
    stride = 20;
    bval = bg[t * 20 + g];
  }
  for (int j = 0; j < 4; j++) {
    int k = tid + j * 256;
    float v = src ? src[(size_t)k * stride] : 0.f;
    Wpack[(size_t)(k >> 5) * STEP_SHORTS + ((k >> 3) & 3) * (NCOLP * 8) + n * 8 +
          (k & 7)] = (unsigned short)bf16rne(v);
  }
  if (tid == 0 && n < 352) bias[n] = bval;
}

// Main: 512 threads = 8 waves, 64 rows/block, 1024 blocks, 2 blocks/CU.
// R11 phase-split structure at doubled occupancy: each wave owns 4 mf x
// 3 nt (48 cols) -> acc 48 VGPR; total ~110 regs fits the (512,2) 128-reg
// cap with no spill -> 16 waves/CU (~43% occupancy) for latency hiding.
// Per half-K: [stage 64KB A tile: load->cvt->swizzled ds_write, unroll 2]
// | barrier | [16 K-steps: swizzled ds_read_b128 A + 3 register-B loads
// from L2 Wpack + 12 MFMA, barrier-free] | barrier. Anti-phase h0.
__global__ __launch_bounds__(512, 2) void ple_main(
    const float* __restrict__ x, const unsigned short* __restrict__ Wpack,
    const float* __restrict__ bias, const float* __restrict__ Wc,
    const float* __restrict__ bc, const float* __restrict__ Wv,
    const float* __restrict__ bv, float* __restrict__ out) {
  // A half-tile: 64 rows x 64 segs(16B bf16, XOR-swizzled) = 65536 B.
  // Epilogue z[32][357] (45.7 KB) aliases it after the final barrier.
  __shared__ __align__(16) char smem[65536];
  float* z = (float*)smem;

  const int tid = threadIdx.x;
  const int l = tid & 63, w = tid >> 6;  // wave w -> cols [w*48, w*48+48)
  const int arow = l & 15, ablk = l >> 4;
  const int rowbase = blockIdx.x * 64;
  const int h0 = (int)(blockIdx.x & 1);  // first half processed

  const f32x4 fzero = {0.f, 0.f, 0.f, 0.f};
  f32x4 acc[4][3];
#pragma unroll
  for (int i = 0; i < 4; ++i)
#pragma unroll
    for (int j = 0; j < 3; ++j) acc[i][j] = fzero;

  // B fragment base (per-lane 16B from Wpack; k-order matches A frags).
  const char* bbase = (const char*)Wpack + ablk * SEG_BYTES +
                      (w * 48 + arow) * 16;
  bf16x8 bA[3], bB[3];  // double bank, static indexing only

  // Preload B(first processed k-step).
#pragma unroll
  for (int nt = 0; nt < 3; nt++)
    bA[nt] = *(const bf16x8*)(bbase + (size_t)(h0 * HSTEP) * STEP_BYTES +
                              nt * 256);

  // Stage mapping: per j, wave w covers row w + j*8; lane l = seg l (8 k).
  const char* xbase =
      (const char*)x + (size_t)(rowbase + w) * 4096 + l * 32;

  for (int hh = 0; hh < 2; ++hh) {
    const int half = h0 ^ hh;
    const int nh16 = (hh == 0) ? (half ^ 1) * HSTEP : half * HSTEP;  // next base
    // ---- stage phase: rows w + 8j (j=0..7), load->pack->write per j ----
    {
      const char* xb = xbase + half * 2048;
#pragma unroll 2
      for (int j = 0; j < 8; j++) {
        const float4 f0 = *(const float4*)(xb + (size_t)j * 8 * 4096);
        const float4 f1 = *(const float4*)(xb + (size_t)j * 8 * 4096 + 16);
        const int row = w + j * 8;
        const int segp = (l & 56) | ((l & 7) ^ (row & 7));
        *(uint4*)(smem + row * 1024 + segp * 16) =
            make_uint4(pack2(f0.x, f0.y), pack2(f0.z, f0.w),
                       pack2(f1.x, f1.y), pack2(f1.z, f1.w));
      }
    }
    __syncthreads();  // A half-tile visible to all waves

    // ---- compute phase: 16 K-steps, barrier-free, LDS + B-regs only ----
    // STEP(ksl): issue B(next processed k) -> bn_, MFMA with bc_ (= B(kk)).
#define STEP(ksl, bc_, bn_)                                                    \
  {                                                                            \
    const int kk = half * HSTEP + (ksl);                                       \
    const int kn = ((ksl) < 15) ? kk + 1 : nh16;                               \
    const char* bp = bbase + (size_t)kn * STEP_BYTES;                          \
    _Pragma("unroll") for (int nt = 0; nt < 3; nt++)                           \
        bn_[nt] = *(const bf16x8*)(bp + nt * 256);                             \
    _Pragma("unroll") for (int mf = 0; mf < 4; mf++) {                         \
      const int s = (ksl)*4 + ablk;                                            \
      const int sgp = (s & 56) | ((s & 7) ^ (arow & 7));                       \
      const bf16x8 av =                                                        \
          *(const bf16x8*)(smem + (mf * 16 + arow) * 1024 + sgp * 16);         \
      _Pragma("unroll") for (int nt = 0; nt < 3; nt++)                         \
          acc[mf][nt] = __builtin_amdgcn_mfma_f32_16x16x32_bf16(               \
              av, bc_[nt], acc[mf][nt], 0, 0, 0);                              \
    }                                                                          \
  }
#pragma unroll
    for (int kp = 0; kp < 8; kp++) {
      STEP(2 * kp, bA, bB)
      STEP(2 * kp + 1, bB, bA)
    }
#undef STEP
    __syncthreads();  // all reads done before next stage / epilogue reuse
  }

  // ---- epilogue: 2 phases of 32 rows. D layout: row=(l>>4)*4+reg, col=l&15.
#pragma unroll
  for (int p = 0; p < 2; p++) {
    __syncthreads();
#pragma unroll
    for (int q = 0; q < 2; q++) {
      const int mf = p * 2 + q;
#pragma unroll
      for (int nt = 0; nt < 3; nt++) {
        if (w == 7 && nt >= 1) continue;  // cols >= 352 are zero pad
#pragma unroll
        for (int r = 0; r < 4; r++)
          z[(q * 16 + ablk * 4 + r) * 357 + w * 48 + nt * 16 + arow] =
              acc[mf][nt][r];
      }
    }
    __syncthreads();
    if (tid < 64) {
      const int t = tid >> 5, r = tid & 31;
      const float* zr = &z[r * 357];
      float gl[20], m = -1e30f;
#pragma unroll
      for (int u = 0; u < 20; u++) {
        gl[u] = zr[300 + t * 20 + u] + bias[300 + t * 20 + u];
        m = fmaxf(m, gl[u]);
      }
      float pr[20], s = 0.f;
#pragma unroll
      for (int u = 0; u < 20; u++) {
        pr[u] = __expf(gl[u] - m);
        s += pr[u];
      }
      const float inv = 1.f / s;
      const float* Wl = t ? Wv : Wc;
      float wl[10];
#pragma unroll
      for (int h = 0; h < 10; h++) wl[h] = Wl[h];
      float accum = 0.f;
#pragma unroll
      for (int u = 0; u < 10; u++) {
        float d = 0.f;
#pragma unroll
        for (int h = 0; h < 10; h++) {
          int c = t * 100 + u * 10 + h;
          d += fmaxf(zr[c] + bias[c], 0.f) * wl[h];
        }
        accum += pr[u] * d;
      }
#pragma unroll
      for (int u = 0; u < 10; u++) {
        float d = 0.f;
#pragma unroll
        for (int h = 0; h < 10; h++) {
          int c = 200 + u * 10 + h;
          d += fmaxf(zr[c] + bias[c], 0.f) * wl[h];
        }
        accum += pr[10 + u] * d;
      }
      float logit = (t ? bv[0] : bc[0]) + accum * inv;
      out[(size_t)t * BROWS + rowbase + p * 32 + r] =
          1.f / (1.f + __expf(-logit));
    }
  }
}

extern "C" void kernel_launch(void* const* d_in, const int* in_sizes, int n_in,
                              void* d_out, int out_size, void* d_ws, size_t ws_size,
                              hipStream_t stream) {
  const float* x = (const float*)d_in[0];
  const float* Ws = (const float*)d_in[3];
  const float* bs = (const float*)d_in[4];
  const float* Wt = (const float*)d_in[5];
  const float* bt = (const float*)d_in[6];
  const float* Wg = (const float*)d_in[7];
  const float* bg = (const float*)d_in[8];
  const float* Wc = (const float*)d_in[9];
  const float* bc = (const float*)d_in[10];
  const float* Wv = (const float*)d_in[11];
  const float* bv = (const float*)d_in[12];
  unsigned short* Wpack = (unsigned short*)d_ws;
  float* bias = (float*)((char*)d_ws + (size_t)NCOLP * 1024 * 2);
  float* out = (float*)d_out;

  hipLaunchKernelGGL(ple_prep, dim3(NCOLP), dim3(256), 0, stream, Ws, bs, Wt, bt,
                     Wg, bg, Wpack, bias);
  hipLaunchKernelGGL(ple_main, dim3(BROWS / 64), dim3(512), 0, stream, x, Wpack,
                     bias, Wc, bc, Wv, bv, out);
}

// Round 17
// 96.379 us; speedup vs baseline: 1.2540x; 1.2540x over previous
//
#include <hip/hip_runtime.h>
#include <hip/hip_bf16.h>

typedef __attribute__((ext_vector_type(8))) short bf16x8;
typedef __attribute__((ext_vector_type(4))) float f32x4;

#define NCOLP 384                 // padded columns (352 real + 32 zero)
#define STEP_SHORTS (NCOLP * 32)  // 12288 shorts = 24576 B per 32-k step
#define STEP_BYTES 24576
#define SEG_BYTES 6144            // Wpack per-ablk segment: 384 cols * 8k * 2B
#define NSTEP 32
#define HSTEP 16
#define BROWS 65536

static __device__ __forceinline__ unsigned int bf16rne(float f) {
  unsigned int u = __float_as_uint(f);
  return (u + 0x7FFFu + ((u >> 16) & 1u)) >> 16;
}
static __device__ __forceinline__ unsigned int pack2(float a, float b) {
  return bf16rne(a) | (bf16rne(b) << 16);
}

// Wpack layout: [step][ablk(4)][col(384)][k%8] (bf16), 24576 B/step.
// Column map: [0,100) task0 (e*10+h), [100,200) task1, [200,300) shared,
// [300,340) gates (t*20+g), [340,384) zero pad.
__global__ void ple_prep(const float* __restrict__ Ws, const float* __restrict__ bs,
                         const float* __restrict__ Wt, const float* __restrict__ bt,
                         const float* __restrict__ Wg, const float* __restrict__ bg,
                         unsigned short* __restrict__ Wpack, float* __restrict__ bias) {
  const int n = blockIdx.x;  // 0..383
  const int tid = threadIdx.x;
  const float* src = nullptr;
  int stride = 0;
  float bval = 0.f;
  if (n < 200) {
    int t = n / 100, m = n % 100, e = m / 10, h = m % 10;
    src = Wt + (size_t)(t * 10 + e) * 10240 + h;
    stride = 10;
    bval = bt[(t * 10 + e) * 10 + h];
  } else if (n < 300) {
    int m = n - 200, e = m / 10, h = m % 10;
    src = Ws + (size_t)e * 10240 + h;
    stride = 10;
    bval = bs[e * 10 + h];
  } else if (n < 340) {
    int m = n - 300, t = m / 20, g = m % 20;
    src = Wg + (size_t)t * 20480 + g;
    stride = 20;
    bval = bg[t * 20 + g];
  }
  for (int j = 0; j < 4; j++) {
    int k = tid + j * 256;
    float v = src ? src[(size_t)k * stride] : 0.f;
    Wpack[(size_t)(k >> 5) * STEP_SHORTS + ((k >> 3) & 3) * (NCOLP * 8) + n * 8 +
          (k & 7)] = (unsigned short)bf16rne(v);
  }
  if (tid == 0 && n < 352) bias[n] = bval;
}

// Main: 512 threads = 8 waves, 64 rows/block, 1024 blocks.
// R16 structure with the register budget FIXED for occupancy: each wave
// owns 4 mf x 3 nt (48 acc) and B is SINGLE-step (24 regs, loaded at step
// top; compiler pipelines under the cap). Combined ~112 <= 128 ->
// __launch_bounds__(512,4): 4 waves/SIMD, 2 blocks/CU, 16 waves/CU (~50%).
// Per half-K: [stage 64KB A tile] | barrier | [16 barrier-free K-steps:
// swizzled ds_read_b128 A + 3 B-loads from L2 Wpack + 12 MFMA] | barrier.
__global__ __launch_bounds__(512, 4) void ple_main(
    const float* __restrict__ x, const unsigned short* __restrict__ Wpack,
    const float* __restrict__ bias, const float* __restrict__ Wc,
    const float* __restrict__ bc, const float* __restrict__ Wv,
    const float* __restrict__ bv, float* __restrict__ out) {
  // A half-tile: 64 rows x 64 segs(16B bf16, XOR-swizzled) = 65536 B.
  // Epilogue z[32][357] (45.7 KB) aliases it after the final barrier.
  __shared__ __align__(16) char smem[65536];
  float* z = (float*)smem;

  const int tid = threadIdx.x;
  const int l = tid & 63, w = tid >> 6;  // wave w -> cols [w*48, w*48+48)
  const int arow = l & 15, ablk = l >> 4;
  const int rowbase = blockIdx.x * 64;
  const int h0 = (int)(blockIdx.x & 1);  // first half processed (stagger)

  const f32x4 fzero = {0.f, 0.f, 0.f, 0.f};
  f32x4 acc[4][3];
#pragma unroll
  for (int i = 0; i < 4; ++i)
#pragma unroll
    for (int j = 0; j < 3; ++j) acc[i][j] = fzero;

  // B fragment base (per-lane 16B from Wpack; k-order matches A frags).
  const char* bbase = (const char*)Wpack + ablk * SEG_BYTES +
                      (w * 48 + arow) * 16;

  // Stage mapping: per j, wave w covers row w + j*8; lane l = seg l (8 k).
  const char* xbase =
      (const char*)x + (size_t)(rowbase + w) * 4096 + l * 32;

  for (int hh = 0; hh < 2; ++hh) {
    const int half = h0 ^ hh;
    // ---- stage phase: rows w + 8j (j=0..7), load->pack->write per j ----
    {
      const char* xb = xbase + half * 2048;
#pragma unroll 2
      for (int j = 0; j < 8; j++) {
        const float4 f0 = *(const float4*)(xb + (size_t)j * 8 * 4096);
        const float4 f1 = *(const float4*)(xb + (size_t)j * 8 * 4096 + 16);
        const int row = w + j * 8;
        const int segp = (l & 56) | ((l & 7) ^ (row & 7));
        *(uint4*)(smem + row * 1024 + segp * 16) =
            make_uint4(pack2(f0.x, f0.y), pack2(f0.z, f0.w),
                       pack2(f1.x, f1.y), pack2(f1.z, f1.w));
      }
    }
    __syncthreads();  // A half-tile visible to all waves

    // ---- compute phase: 16 K-steps, barrier-free, LDS + B-regs only ----
#define STEP(ksl)                                                              \
  {                                                                            \
    const int kk = half * HSTEP + (ksl);                                       \
    const char* bp = bbase + (size_t)kk * STEP_BYTES;                          \
    const bf16x8 b0 = *(const bf16x8*)(bp);                                    \
    const bf16x8 b1 = *(const bf16x8*)(bp + 256);                              \
    const bf16x8 b2 = *(const bf16x8*)(bp + 512);                              \
    _Pragma("unroll") for (int mf = 0; mf < 4; mf++) {                         \
      const int s = (ksl)*4 + ablk;                                            \
      const int sgp = (s & 56) | ((s & 7) ^ (arow & 7));                       \
      const bf16x8 av =                                                        \
          *(const bf16x8*)(smem + (mf * 16 + arow) * 1024 + sgp * 16);         \
      acc[mf][0] =                                                             \
          __builtin_amdgcn_mfma_f32_16x16x32_bf16(av, b0, acc[mf][0], 0, 0, 0);\
      acc[mf][1] =                                                             \
          __builtin_amdgcn_mfma_f32_16x16x32_bf16(av, b1, acc[mf][1], 0, 0, 0);\
      acc[mf][2] =                                                             \
          __builtin_amdgcn_mfma_f32_16x16x32_bf16(av, b2, acc[mf][2], 0, 0, 0);\
    }                                                                          \
  }
#pragma unroll
    for (int ks = 0; ks < HSTEP; ks++) {
      STEP(ks)
    }
#undef STEP
    __syncthreads();  // all reads done before next stage / epilogue reuse
  }

  // ---- epilogue: 2 phases of 32 rows. D layout: row=(l>>4)*4+reg, col=l&15.
#pragma unroll
  for (int p = 0; p < 2; p++) {
    __syncthreads();
#pragma unroll
    for (int q = 0; q < 2; q++) {
      const int mf = p * 2 + q;
#pragma unroll
      for (int nt = 0; nt < 3; nt++) {
        if (w == 7 && nt >= 1) continue;  // cols >= 352 are zero pad
#pragma unroll
        for (int r = 0; r < 4; r++)
          z[(q * 16 + ablk * 4 + r) * 357 + w * 48 + nt * 16 + arow] =
              acc[mf][nt][r];
      }
    }
    __syncthreads();
    if (tid < 64) {
      const int t = tid >> 5, r = tid & 31;
      const float* zr = &z[r * 357];
      float gl[20], m = -1e30f;
#pragma unroll
      for (int u = 0; u < 20; u++) {
        gl[u] = zr[300 + t * 20 + u] + bias[300 + t * 20 + u];
        m = fmaxf(m, gl[u]);
      }
      float pr[20], s = 0.f;
#pragma unroll
      for (int u = 0; u < 20; u++) {
        pr[u] = __expf(gl[u] - m);
        s += pr[u];
      }
      const float inv = 1.f / s;
      const float* Wl = t ? Wv : Wc;
      float wl[10];
#pragma unroll
      for (int h = 0; h < 10; h++) wl[h] = Wl[h];
      float accum = 0.f;
#pragma unroll
      for (int u = 0; u < 10; u++) {
        float d = 0.f;
#pragma unroll
        for (int h = 0; h < 10; h++) {
          int c = t * 100 + u * 10 + h;
          d += fmaxf(zr[c] + bias[c], 0.f) * wl[h];
        }
        accum += pr[u] * d;
      }
#pragma unroll
      for (int u = 0; u < 10; u++) {
        float d = 0.f;
#pragma unroll
        for (int h = 0; h < 10; h++) {
          int c = 200 + u * 10 + h;
          d += fmaxf(zr[c] + bias[c], 0.f) * wl[h];
        }
        accum += pr[10 + u] * d;
      }
      float logit = (t ? bv[0] : bc[0]) + accum * inv;
      out[(size_t)t * BROWS + rowbase + p * 32 + r] =
          1.f / (1.f + __expf(-logit));
    }
  }
}

extern "C" void kernel_launch(void* const* d_in, const int* in_sizes, int n_in,
                              void* d_out, int out_size, void* d_ws, size_t ws_size,
                              hipStream_t stream) {
  const float* x = (const float*)d_in[0];
  const float* Ws = (const float*)d_in[3];
  const float* bs = (const float*)d_in[4];
  const float* Wt = (const float*)d_in[5];
  const float* bt = (const float*)d_in[6];
  const float* Wg = (const float*)d_in[7];
  const float* bg = (const float*)d_in[8];
  const float* Wc = (const float*)d_in[9];
  const float* bc = (const float*)d_in[10];
  const float* Wv = (const float*)d_in[11];
  const float* bv = (const float*)d_in[12];
  unsigned short* Wpack = (unsigned short*)d_ws;
  float* bias = (float*)((char*)d_ws + (size_t)NCOLP * 1024 * 2);
  float* out = (float*)d_out;

  hipLaunchKernelGGL(ple_prep, dim3(NCOLP), dim3(256), 0, stream, Ws, bs, Wt, bt,
                     Wg, bg, Wpack, bias);
  hipLaunchKernelGGL(ple_main, dim3(BROWS / 64), dim3(512), 0, stream, x, Wpack,
                     bias, Wc, bc, Wv, bv, out);
}